// Round 2
// baseline (2877.404 us; speedup 1.0000x reference)
//
#include <hip/hip_runtime.h>

#define B_ 4
#define T_ 2048
#define C_ 1024
#define H_ 16
#define D_ 64
#define EPS_ 1.1920929e-07f

// ---------------- GEMM: Y = X @ W^T ----------------
// X: (M,K) row-major, W: (N,K) row-major, Y: (M,N) row-major.
// 64x64 tile per block, 256 threads, 4x4 accumulators per thread.
__global__ __launch_bounds__(256) void gemm_bt(const float* __restrict__ X,
                                               const float* __restrict__ W,
                                               float* __restrict__ Y,
                                               int M, int N, int K) {
  __shared__ float Xs[64][17];
  __shared__ float Ws[64][17];
  const int tid = threadIdx.x;
  const int tx = tid & 15, ty = tid >> 4;
  const int m0 = blockIdx.y * 64, n0 = blockIdx.x * 64;
  const int lrow = tid >> 2, lcol = (tid & 3) * 4;
  float acc[4][4] = {};
  for (int kt = 0; kt < K; kt += 16) {
    float4 xv = *(const float4*)&X[(size_t)(m0 + lrow) * K + kt + lcol];
    float4 wv = *(const float4*)&W[(size_t)(n0 + lrow) * K + kt + lcol];
    Xs[lrow][lcol + 0] = xv.x; Xs[lrow][lcol + 1] = xv.y;
    Xs[lrow][lcol + 2] = xv.z; Xs[lrow][lcol + 3] = xv.w;
    Ws[lrow][lcol + 0] = wv.x; Ws[lrow][lcol + 1] = wv.y;
    Ws[lrow][lcol + 2] = wv.z; Ws[lrow][lcol + 3] = wv.w;
    __syncthreads();
#pragma unroll
    for (int kk = 0; kk < 16; ++kk) {
      float a[4], b[4];
#pragma unroll
      for (int r = 0; r < 4; ++r) a[r] = Xs[ty * 4 + r][kk];
#pragma unroll
      for (int c = 0; c < 4; ++c) b[c] = Ws[tx * 4 + c][kk];
#pragma unroll
      for (int r = 0; r < 4; ++r)
#pragma unroll
        for (int c = 0; c < 4; ++c) acc[r][c] += a[r] * b[c];
    }
    __syncthreads();
  }
#pragma unroll
  for (int r = 0; r < 4; ++r)
#pragma unroll
    for (int c = 0; c < 4; ++c)
      Y[(size_t)(m0 + ty * 4 + r) * N + n0 + tx * 4 + c] = acc[r][c];
}

// ---------------- fused RoPE + RMSNorm (in place) ----------------
// buf layout: (B, T, H, D) contiguous; one 64-lane wave per (b,t,h) row.
__global__ __launch_bounds__(256) void rope_rms(float* __restrict__ buf,
                                                const float* __restrict__ cs,
                                                const float* __restrict__ sn) {
  const int row = blockIdx.x * 4 + (threadIdx.x >> 6);
  const int lane = threadIdx.x & 63;
  const int t = (row / H_) % T_;
  const size_t base = (size_t)row * 64;
  float v = buf[base + lane];
  float p = __shfl_xor(v, 32, 64);  // rotation partner (lane ^ 32)
  const int idx = lane & 31;
  const float c = cs[t * 32 + idx], s = sn[t * 32 + idx];
  // lane<32: x1*cos + x2*sin ; lane>=32: -x1*sin + x2*cos  (x1=low half, x2=high half)
  float o = (lane < 32) ? (v * c + p * s) : (v * c - p * s);
  float sq = o * o;
#pragma unroll
  for (int m = 1; m < 64; m <<= 1) sq += __shfl_xor(sq, m, 64);
  const float r = rsqrtf(sq * (1.0f / 64.0f) + EPS_);
  buf[base + lane] = o * r;
}

// ---------------- flash attention ----------------
// Q,K,V,Y layout: (B, T, H, D). grid = (T/64, B*H), block = 256.
// Each block: 64 queries of one (b,h); iterate 64-key tiles, online softmax.
__global__ __launch_bounds__(256) void flash_attn(const float* __restrict__ Q,
                                                  const float* __restrict__ K,
                                                  const float* __restrict__ V,
                                                  float* __restrict__ Y) {
  __shared__ float Qs[64][65];
  __shared__ float KVs[64][65];  // holds K tile, then reused for V tile
  __shared__ float Ss[64][65];
  __shared__ float mS[64], lS[64], aS[64];
  const int tid = threadIdx.x;
  const int tx = tid & 15, ty = tid >> 4;
  const int qt = blockIdx.x;
  const int bh = blockIdx.y;
  const int b = bh >> 4, h = bh & 15;

  // load Q tile (rows = queries, cols = head dim)
  {
    const int i = tid >> 2, d4 = (tid & 3) * 16;
    const size_t gbase = ((size_t)((b * T_ + qt * 64 + i) * H_ + h)) * D_;
#pragma unroll
    for (int u = 0; u < 16; u += 4) {
      float4 qv = *(const float4*)&Q[gbase + d4 + u];
      Qs[i][d4 + u + 0] = qv.x; Qs[i][d4 + u + 1] = qv.y;
      Qs[i][d4 + u + 2] = qv.z; Qs[i][d4 + u + 3] = qv.w;
    }
  }
  if (tid < 64) { mS[tid] = -1e30f; lS[tid] = 0.0f; }
  float acc[4][4] = {};  // O accumulator: rows ty*4+r, dims tx*4+c
  __syncthreads();

  for (int kt = 0; kt < T_; kt += 64) {
    // load K tile
    {
      const int j = tid >> 2, d4 = (tid & 3) * 16;
      const size_t gbase = ((size_t)((b * T_ + kt + j) * H_ + h)) * D_;
#pragma unroll
      for (int u = 0; u < 16; u += 4) {
        float4 kv = *(const float4*)&K[gbase + d4 + u];
        KVs[j][d4 + u + 0] = kv.x; KVs[j][d4 + u + 1] = kv.y;
        KVs[j][d4 + u + 2] = kv.z; KVs[j][d4 + u + 3] = kv.w;
      }
    }
    __syncthreads();
    // S = (Q K^T) * scale
    float s[4][4] = {};
#pragma unroll
    for (int d = 0; d < 64; ++d) {
      float a[4], bb[4];
#pragma unroll
      for (int r = 0; r < 4; ++r) a[r] = Qs[ty * 4 + r][d];
#pragma unroll
      for (int c = 0; c < 4; ++c) bb[c] = KVs[tx * 4 + c][d];
#pragma unroll
      for (int r = 0; r < 4; ++r)
#pragma unroll
        for (int c = 0; c < 4; ++c) s[r][c] += a[r] * bb[c];
    }
#pragma unroll
    for (int r = 0; r < 4; ++r)
#pragma unroll
      for (int c = 0; c < 4; ++c)
        Ss[ty * 4 + r][tx * 4 + c] = s[r][c] * 0.125f;
    __syncthreads();
    // online softmax: 4 threads per row
    {
      const int r = tid >> 2, sub = tid & 3;
      float mx = -1e30f;
      for (int j = sub * 16; j < sub * 16 + 16; ++j) mx = fmaxf(mx, Ss[r][j]);
      mx = fmaxf(mx, __shfl_xor(mx, 1, 64));
      mx = fmaxf(mx, __shfl_xor(mx, 2, 64));
      const float m_old = mS[r];
      const float m_new = fmaxf(m_old, mx);
      float sum = 0.f;
      for (int j = sub * 16; j < sub * 16 + 16; ++j) {
        float pv = __expf(Ss[r][j] - m_new);
        Ss[r][j] = pv;
        sum += pv;
      }
      sum += __shfl_xor(sum, 1, 64);
      sum += __shfl_xor(sum, 2, 64);
      if (sub == 0) {
        aS[r] = __expf(m_old - m_new);
        lS[r] = lS[r] * __expf(m_old - m_new) + sum;
        mS[r] = m_new;
      }
    }
    __syncthreads();
    // rescale accumulator
    {
      float al[4];
#pragma unroll
      for (int r = 0; r < 4; ++r) al[r] = aS[ty * 4 + r];
#pragma unroll
      for (int r = 0; r < 4; ++r)
#pragma unroll
        for (int c = 0; c < 4; ++c) acc[r][c] *= al[r];
    }
    // load V tile into KVs (all reads of K tile finished before last barrier)
    {
      const int j = tid >> 2, d4 = (tid & 3) * 16;
      const size_t gbase = ((size_t)((b * T_ + kt + j) * H_ + h)) * D_;
#pragma unroll
      for (int u = 0; u < 16; u += 4) {
        float4 vv = *(const float4*)&V[gbase + d4 + u];
        KVs[j][d4 + u + 0] = vv.x; KVs[j][d4 + u + 1] = vv.y;
        KVs[j][d4 + u + 2] = vv.z; KVs[j][d4 + u + 3] = vv.w;
      }
    }
    __syncthreads();
    // O += P @ V
#pragma unroll
    for (int j = 0; j < 64; ++j) {
      float p[4], vv[4];
#pragma unroll
      for (int r = 0; r < 4; ++r) p[r] = Ss[ty * 4 + r][j];
#pragma unroll
      for (int c = 0; c < 4; ++c) vv[c] = KVs[j][tx * 4 + c];
#pragma unroll
      for (int r = 0; r < 4; ++r)
#pragma unroll
        for (int c = 0; c < 4; ++c) acc[r][c] += p[r] * vv[c];
    }
    __syncthreads();
  }
  // epilogue: normalize by l, store
#pragma unroll
  for (int r = 0; r < 4; ++r) {
    const float li = 1.0f / lS[ty * 4 + r];
    const int t = qt * 64 + ty * 4 + r;
    const size_t gbase = ((size_t)((b * T_ + t) * H_ + h)) * D_;
#pragma unroll
    for (int c = 0; c < 4; ++c)
      Y[gbase + tx * 4 + c] = acc[r][c] * li;
  }
}

extern "C" void kernel_launch(void* const* d_in, const int* in_sizes, int n_in,
                              void* d_out, int out_size, void* d_ws, size_t ws_size,
                              hipStream_t stream) {
  const float* x    = (const float*)d_in[0];
  const float* cosb = (const float*)d_in[1];
  const float* sinb = (const float*)d_in[2];
  const float* Wq   = (const float*)d_in[3];
  const float* Wk   = (const float*)d_in[4];
  const float* Wv   = (const float*)d_in[5];
  const float* Wo   = (const float*)d_in[6];
  float* out = (float*)d_out;

  const size_t NE = (size_t)B_ * T_ * C_;  // 8M elements
  float* q = (float*)d_ws;
  float* k = q + NE;
  float* v = k + NE;
  float* y = v + NE;

  const int M = B_ * T_;
  dim3 gg(C_ / 64, M / 64), gb(256);
  gemm_bt<<<gg, gb, 0, stream>>>(x, Wq, q, M, C_, C_);
  gemm_bt<<<gg, gb, 0, stream>>>(x, Wk, k, M, C_, C_);
  gemm_bt<<<gg, gb, 0, stream>>>(x, Wv, v, M, C_, C_);

  dim3 rg((M * H_) / 4);
  rope_rms<<<rg, 256, 0, stream>>>(q, cosb, sinb);
  rope_rms<<<rg, 256, 0, stream>>>(k, cosb, sinb);

  dim3 fg(T_ / 64, B_ * H_);
  flash_attn<<<fg, 256, 0, stream>>>(q, k, v, y);

  gemm_bt<<<gg, gb, 0, stream>>>(y, Wo, out, M, C_, C_);
}

// Round 5
// 1681.139 us; speedup vs baseline: 1.7116x; 1.7116x over previous
//
#include <hip/hip_runtime.h>

#define B_ 4
#define T_ 2048
#define C_ 1024
#define H_ 16
#define D_ 64
#define EPS_ 1.1920929e-07f

typedef __attribute__((ext_vector_type(8))) short bf16x8;
typedef __attribute__((ext_vector_type(4))) float f32x4;

__device__ inline unsigned short f2bf(float f) {
  unsigned u = __float_as_uint(f);
  unsigned r = (u + 0x7fffu + ((u >> 16) & 1u)) >> 16;
  return (unsigned short)r;
}

// ---------------- f32 -> bf16 conversion ----------------
__global__ __launch_bounds__(256) void cvt_bf16(const float* __restrict__ src,
                                                unsigned short* __restrict__ dst,
                                                int n) {
  const int i = (blockIdx.x * 256 + threadIdx.x) * 4;
  if (i < n) {
    float4 v = *(const float4*)&src[i];
    ushort4 o;
    o.x = f2bf(v.x); o.y = f2bf(v.y); o.z = f2bf(v.z); o.w = f2bf(v.w);
    *(ushort4*)&dst[i] = o;
  }
}

// ---------------- bf16 MFMA GEMM: Y = X @ W^T ----------------
// X: (M,K) bf16 row-major, W: (N,K) bf16 row-major, Y: (M,N) f32 row-major.
// 128x128 tile, BK=64, 256 threads = 4 waves (2x2), each wave 64x64 out.
// Staging: register round-trip (16B global load -> ds_write_b128); no
// global_load_lds this round (suspected container-killer, isolating).
__global__ __launch_bounds__(256) void gemm_bf16(const unsigned short* __restrict__ X,
                                                 const unsigned short* __restrict__ W,
                                                 float* __restrict__ Y,
                                                 int M, int N, int K) {
  __shared__ short As[128 * 64];  // row-major [128][64]
  __shared__ short Bs[128 * 64];
  const int tid = threadIdx.x;
  const int lane = tid & 63;
  const int w = tid >> 6;          // wave 0..3
  const int wr = w >> 1, wc = w & 1;
  const int m0 = blockIdx.y * 128, n0 = blockIdx.x * 128;
  const int srow = lane >> 3;      // 0..7: row within 8-row staging group
  const int scol = (lane & 7) * 8; // bf16 col offset 0..56

  f32x4 acc[4][4];
#pragma unroll
  for (int mi = 0; mi < 4; ++mi)
#pragma unroll
    for (int ni = 0; ni < 4; ++ni)
      acc[mi][ni] = (f32x4){0.f, 0.f, 0.f, 0.f};

  const int r = lane & 15;     // row (A) / col-index n (B) within 16-tile
  const int quad = lane >> 4;  // k-chunk selector

  for (int kt = 0; kt < K; kt += 64) {
    // stage A,B tiles: wave w covers rows [w*32, w*32+32), 4 iters x 8 rows
#pragma unroll
    for (int i = 0; i < 4; ++i) {
      const int row = w * 32 + i * 8 + srow;
      bf16x8 av = *(const bf16x8*)&X[(size_t)(m0 + row) * K + kt + scol];
      bf16x8 bv = *(const bf16x8*)&W[(size_t)(n0 + row) * K + kt + scol];
      *(bf16x8*)&As[row * 64 + scol] = av;
      *(bf16x8*)&Bs[row * 64 + scol] = bv;
    }
    __syncthreads();

#pragma unroll
    for (int kc = 0; kc < 2; ++kc) {
      const int ko = kc * 32 + quad * 8;
      bf16x8 a[4], b[4];
#pragma unroll
      for (int mi = 0; mi < 4; ++mi)
        a[mi] = *(const bf16x8*)&As[(wr * 64 + mi * 16 + r) * 64 + ko];
#pragma unroll
      for (int ni = 0; ni < 4; ++ni)
        b[ni] = *(const bf16x8*)&Bs[(wc * 64 + ni * 16 + r) * 64 + ko];
#pragma unroll
      for (int mi = 0; mi < 4; ++mi)
#pragma unroll
        for (int ni = 0; ni < 4; ++ni)
          acc[mi][ni] = __builtin_amdgcn_mfma_f32_16x16x32_bf16(a[mi], b[ni], acc[mi][ni], 0, 0, 0);
    }
    __syncthreads();
  }

  // epilogue: C/D layout col=lane&15, row=quad*4+j (verified m89/m91)
#pragma unroll
  for (int mi = 0; mi < 4; ++mi)
#pragma unroll
    for (int ni = 0; ni < 4; ++ni) {
      const int gc = n0 + wc * 64 + ni * 16 + r;
#pragma unroll
      for (int j = 0; j < 4; ++j) {
        const int gr = m0 + wr * 64 + mi * 16 + quad * 4 + j;
        Y[(size_t)gr * N + gc] = acc[mi][ni][j];
      }
    }
}

// ---------------- fused RoPE + RMSNorm (in place, fp32) ----------------
__global__ __launch_bounds__(256) void rope_rms(float* __restrict__ buf,
                                                const float* __restrict__ cs,
                                                const float* __restrict__ sn) {
  const int row = blockIdx.x * 4 + (threadIdx.x >> 6);
  const int lane = threadIdx.x & 63;
  const int t = (row / H_) % T_;
  const size_t base = (size_t)row * 64;
  float v = buf[base + lane];
  float p = __shfl_xor(v, 32, 64);
  const int idx = lane & 31;
  const float c = cs[t * 32 + idx], s = sn[t * 32 + idx];
  float o = (lane < 32) ? (v * c + p * s) : (v * c - p * s);
  float sq = o * o;
#pragma unroll
  for (int m = 1; m < 64; m <<= 1) sq += __shfl_xor(sq, m, 64);
  const float r = rsqrtf(sq * (1.0f / 64.0f) + EPS_);
  buf[base + lane] = o * r;
}

// ---------------- flash attention (fp32, unchanged from round 2) ----------------
__global__ __launch_bounds__(256) void flash_attn(const float* __restrict__ Q,
                                                  const float* __restrict__ K,
                                                  const float* __restrict__ V,
                                                  float* __restrict__ Y) {
  __shared__ float Qs[64][65];
  __shared__ float KVs[64][65];
  __shared__ float Ss[64][65];
  __shared__ float mS[64], lS[64], aS[64];
  const int tid = threadIdx.x;
  const int tx = tid & 15, ty = tid >> 4;
  const int qt = blockIdx.x;
  const int bh = blockIdx.y;
  const int b = bh >> 4, h = bh & 15;

  {
    const int i = tid >> 2, d4 = (tid & 3) * 16;
    const size_t gbase = ((size_t)((b * T_ + qt * 64 + i) * H_ + h)) * D_;
#pragma unroll
    for (int u = 0; u < 16; u += 4) {
      float4 qv = *(const float4*)&Q[gbase + d4 + u];
      Qs[i][d4 + u + 0] = qv.x; Qs[i][d4 + u + 1] = qv.y;
      Qs[i][d4 + u + 2] = qv.z; Qs[i][d4 + u + 3] = qv.w;
    }
  }
  if (tid < 64) { mS[tid] = -1e30f; lS[tid] = 0.0f; }
  float acc[4][4] = {};
  __syncthreads();

  for (int kt = 0; kt < T_; kt += 64) {
    {
      const int j = tid >> 2, d4 = (tid & 3) * 16;
      const size_t gbase = ((size_t)((b * T_ + kt + j) * H_ + h)) * D_;
#pragma unroll
      for (int u = 0; u < 16; u += 4) {
        float4 kv = *(const float4*)&K[gbase + d4 + u];
        KVs[j][d4 + u + 0] = kv.x; KVs[j][d4 + u + 1] = kv.y;
        KVs[j][d4 + u + 2] = kv.z; KVs[j][d4 + u + 3] = kv.w;
      }
    }
    __syncthreads();
    float s[4][4] = {};
#pragma unroll
    for (int d = 0; d < 64; ++d) {
      float a[4], bb[4];
#pragma unroll
      for (int rr = 0; rr < 4; ++rr) a[rr] = Qs[ty * 4 + rr][d];
#pragma unroll
      for (int c = 0; c < 4; ++c) bb[c] = KVs[tx * 4 + c][d];
#pragma unroll
      for (int rr = 0; rr < 4; ++rr)
#pragma unroll
        for (int c = 0; c < 4; ++c) s[rr][c] += a[rr] * bb[c];
    }
#pragma unroll
    for (int rr = 0; rr < 4; ++rr)
#pragma unroll
      for (int c = 0; c < 4; ++c)
        Ss[ty * 4 + rr][tx * 4 + c] = s[rr][c] * 0.125f;
    __syncthreads();
    {
      const int rr = tid >> 2, sub = tid & 3;
      float mx = -1e30f;
      for (int j = sub * 16; j < sub * 16 + 16; ++j) mx = fmaxf(mx, Ss[rr][j]);
      mx = fmaxf(mx, __shfl_xor(mx, 1, 64));
      mx = fmaxf(mx, __shfl_xor(mx, 2, 64));
      const float m_old = mS[rr];
      const float m_new = fmaxf(m_old, mx);
      float sum = 0.f;
      for (int j = sub * 16; j < sub * 16 + 16; ++j) {
        float pv = __expf(Ss[rr][j] - m_new);
        Ss[rr][j] = pv;
        sum += pv;
      }
      sum += __shfl_xor(sum, 1, 64);
      sum += __shfl_xor(sum, 2, 64);
      if (sub == 0) {
        aS[rr] = __expf(m_old - m_new);
        lS[rr] = lS[rr] * __expf(m_old - m_new) + sum;
        mS[rr] = m_new;
      }
    }
    __syncthreads();
    {
      float al[4];
#pragma unroll
      for (int rr = 0; rr < 4; ++rr) al[rr] = aS[ty * 4 + rr];
#pragma unroll
      for (int rr = 0; rr < 4; ++rr)
#pragma unroll
        for (int c = 0; c < 4; ++c) acc[rr][c] *= al[rr];
    }
    {
      const int j = tid >> 2, d4 = (tid & 3) * 16;
      const size_t gbase = ((size_t)((b * T_ + kt + j) * H_ + h)) * D_;
#pragma unroll
      for (int u = 0; u < 16; u += 4) {
        float4 vv = *(const float4*)&V[gbase + d4 + u];
        KVs[j][d4 + u + 0] = vv.x; KVs[j][d4 + u + 1] = vv.y;
        KVs[j][d4 + u + 2] = vv.z; KVs[j][d4 + u + 3] = vv.w;
      }
    }
    __syncthreads();
#pragma unroll
    for (int j = 0; j < 64; ++j) {
      float p[4], vv[4];
#pragma unroll
      for (int rr = 0; rr < 4; ++rr) p[rr] = Ss[ty * 4 + rr][j];
#pragma unroll
      for (int c = 0; c < 4; ++c) vv[c] = KVs[j][tx * 4 + c];
#pragma unroll
      for (int rr = 0; rr < 4; ++rr)
#pragma unroll
        for (int c = 0; c < 4; ++c) acc[rr][c] += p[rr] * vv[c];
    }
    __syncthreads();
  }
#pragma unroll
  for (int rr = 0; rr < 4; ++rr) {
    const float li = 1.0f / lS[ty * 4 + rr];
    const int t = qt * 64 + ty * 4 + rr;
    const size_t gbase = ((size_t)((b * T_ + t) * H_ + h)) * D_;
#pragma unroll
    for (int c = 0; c < 4; ++c)
      Y[gbase + tx * 4 + c] = acc[rr][c] * li;
  }
}

extern "C" void kernel_launch(void* const* d_in, const int* in_sizes, int n_in,
                              void* d_out, int out_size, void* d_ws, size_t ws_size,
                              hipStream_t stream) {
  const float* x    = (const float*)d_in[0];
  const float* cosb = (const float*)d_in[1];
  const float* sinb = (const float*)d_in[2];
  const float* Wq   = (const float*)d_in[3];
  const float* Wk   = (const float*)d_in[4];
  const float* Wv   = (const float*)d_in[5];
  const float* Wo   = (const float*)d_in[6];
  float* out = (float*)d_out;

  const size_t NE = (size_t)B_ * T_ * C_;  // 8M elements
  const int CC = C_ * C_;                  // 1M elements
  // workspace layout (~120 MB): q/k/v fp32 = 96 MB, bf16 bufs = 24 MB
  float* q = (float*)d_ws;
  float* k = q + NE;
  float* v = k + NE;
  unsigned short* xb  = (unsigned short*)(v + NE);   // 16 MB
  unsigned short* yb  = xb;                          // reuse: xb dead after QKV GEMMs
  unsigned short* wqb = xb + NE;
  unsigned short* wkb = wqb + CC;
  unsigned short* wvb = wkb + CC;
  unsigned short* wob = wvb + CC;
  float* y = out;  // stage attention output in d_out; overwritten by final GEMM

  const int M = B_ * T_;  // 8192

  // convert inputs to bf16
  cvt_bf16<<<(int)(NE / 1024), 256, 0, stream>>>(x, xb, (int)NE);
  cvt_bf16<<<CC / 1024, 256, 0, stream>>>(Wq, wqb, CC);
  cvt_bf16<<<CC / 1024, 256, 0, stream>>>(Wk, wkb, CC);
  cvt_bf16<<<CC / 1024, 256, 0, stream>>>(Wv, wvb, CC);
  cvt_bf16<<<CC / 1024, 256, 0, stream>>>(Wo, wob, CC);

  dim3 gg(C_ / 128, M / 128), gb(256);
  gemm_bf16<<<gg, gb, 0, stream>>>(xb, wqb, q, M, C_, C_);
  gemm_bf16<<<gg, gb, 0, stream>>>(xb, wkb, k, M, C_, C_);
  gemm_bf16<<<gg, gb, 0, stream>>>(xb, wvb, v, M, C_, C_);

  dim3 rg((M * H_) / 4);
  rope_rms<<<rg, 256, 0, stream>>>(q, cosb, sinb);
  rope_rms<<<rg, 256, 0, stream>>>(k, cosb, sinb);

  dim3 fg(T_ / 64, B_ * H_);
  flash_attn<<<fg, 256, 0, stream>>>(q, k, v, y);

  cvt_bf16<<<(int)(NE / 1024), 256, 0, stream>>>(y, yb, (int)NE);
  gemm_bf16<<<gg, gb, 0, stream>>>(yb, wob, out, M, C_, C_);
}

// Round 6
// 577.682 us; speedup vs baseline: 4.9809x; 2.9101x over previous
//
#include <hip/hip_runtime.h>

#define B_ 4
#define T_ 2048
#define C_ 1024
#define H_ 16
#define D_ 64
#define EPS_ 1.1920929e-07f

typedef __attribute__((ext_vector_type(8))) short bf16x8;
typedef __attribute__((ext_vector_type(4))) float f32x4;
typedef unsigned short u16;

__device__ inline u16 f2bf(float f) {
  unsigned u = __float_as_uint(f);
  unsigned r = (u + 0x7fffu + ((u >> 16) & 1u)) >> 16;
  return (u16)r;
}

// ---------------- bf16 MFMA GEMM: Y = X @ W^T ----------------
// X,W fp32 (converted to bf16 during LDS staging). Y fp32 or bf16.
// 128x128 tile, BK=64, 256 threads = 4 waves (2x2), each wave 64x64 out.
template <bool BF16OUT>
__global__ __launch_bounds__(256) void gemm_xw(const float* __restrict__ X,
                                               const float* __restrict__ W,
                                               void* __restrict__ Yv,
                                               int M, int N, int K) {
  __shared__ short As[128 * 64];
  __shared__ short Bs[128 * 64];
  const int tid = threadIdx.x;
  const int lane = tid & 63;
  const int w = tid >> 6;
  const int wr = w >> 1, wc = w & 1;
  const int m0 = blockIdx.y * 128, n0 = blockIdx.x * 128;
  const int srow = lane >> 3;
  const int scol = (lane & 7) * 8;

  f32x4 acc[4][4];
#pragma unroll
  for (int mi = 0; mi < 4; ++mi)
#pragma unroll
    for (int ni = 0; ni < 4; ++ni)
      acc[mi][ni] = (f32x4){0.f, 0.f, 0.f, 0.f};

  const int r = lane & 15;
  const int quad = lane >> 4;

  for (int kt = 0; kt < K; kt += 64) {
#pragma unroll
    for (int i = 0; i < 4; ++i) {
      const int row = w * 32 + i * 8 + srow;
      const float* gx = &X[(size_t)(m0 + row) * K + kt + scol];
      const float* gw = &W[(size_t)(n0 + row) * K + kt + scol];
      float4 x0 = *(const float4*)gx, x1 = *(const float4*)(gx + 4);
      float4 w0 = *(const float4*)gw, w1 = *(const float4*)(gw + 4);
      bf16x8 av, bv;
      av[0] = f2bf(x0.x); av[1] = f2bf(x0.y); av[2] = f2bf(x0.z); av[3] = f2bf(x0.w);
      av[4] = f2bf(x1.x); av[5] = f2bf(x1.y); av[6] = f2bf(x1.z); av[7] = f2bf(x1.w);
      bv[0] = f2bf(w0.x); bv[1] = f2bf(w0.y); bv[2] = f2bf(w0.z); bv[3] = f2bf(w0.w);
      bv[4] = f2bf(w1.x); bv[5] = f2bf(w1.y); bv[6] = f2bf(w1.z); bv[7] = f2bf(w1.w);
      *(bf16x8*)&As[row * 64 + scol] = av;
      *(bf16x8*)&Bs[row * 64 + scol] = bv;
    }
    __syncthreads();

#pragma unroll
    for (int kc = 0; kc < 2; ++kc) {
      const int ko = kc * 32 + quad * 8;
      bf16x8 a[4], b[4];
#pragma unroll
      for (int mi = 0; mi < 4; ++mi)
        a[mi] = *(const bf16x8*)&As[(wr * 64 + mi * 16 + r) * 64 + ko];
#pragma unroll
      for (int ni = 0; ni < 4; ++ni)
        b[ni] = *(const bf16x8*)&Bs[(wc * 64 + ni * 16 + r) * 64 + ko];
#pragma unroll
      for (int mi = 0; mi < 4; ++mi)
#pragma unroll
        for (int ni = 0; ni < 4; ++ni)
          acc[mi][ni] = __builtin_amdgcn_mfma_f32_16x16x32_bf16(a[mi], b[ni], acc[mi][ni], 0, 0, 0);
    }
    __syncthreads();
  }

#pragma unroll
  for (int mi = 0; mi < 4; ++mi)
#pragma unroll
    for (int ni = 0; ni < 4; ++ni) {
      const int gc = n0 + wc * 64 + ni * 16 + r;
#pragma unroll
      for (int j = 0; j < 4; ++j) {
        const int gr = m0 + wr * 64 + mi * 16 + quad * 4 + j;
        if (BF16OUT)
          ((u16*)Yv)[(size_t)gr * N + gc] = f2bf(acc[mi][ni][j]);
        else
          ((float*)Yv)[(size_t)gr * N + gc] = acc[mi][ni][j];
      }
    }
}

// ---------------- fused RoPE + RMSNorm: fp32 in -> bf16 out ----------------
__global__ __launch_bounds__(256) void rope_rms(const float* __restrict__ buf,
                                                u16* __restrict__ outb,
                                                const float* __restrict__ cs,
                                                const float* __restrict__ sn) {
  const int row = blockIdx.x * 4 + (threadIdx.x >> 6);
  const int lane = threadIdx.x & 63;
  const int t = (row / H_) % T_;
  const size_t base = (size_t)row * 64;
  float v = buf[base + lane];
  float p = __shfl_xor(v, 32, 64);
  const int idx = lane & 31;
  const float c = cs[t * 32 + idx], s = sn[t * 32 + idx];
  float o = (lane < 32) ? (v * c + p * s) : (v * c - p * s);
  float sq = o * o;
#pragma unroll
  for (int m = 1; m < 64; m <<= 1) sq += __shfl_xor(sq, m, 64);
  const float r = rsqrtf(sq * (1.0f / 64.0f) + EPS_);
  outb[base + lane] = f2bf(o * r);
}

// ---------------- MFMA flash attention ----------------
// Q,K,V bf16 (B,T,H,D). grid=(T/64, B*H), block=256 (4 waves).
// Wave w owns queries [qt*64+w*16, +16). 16x16x32 MFMA throughout.
__global__ __launch_bounds__(256) void flash_mfma(const u16* __restrict__ Qb,
                                                  const u16* __restrict__ Kb,
                                                  const u16* __restrict__ Vb,
                                                  float* __restrict__ Y) {
  __shared__ u16 Ks[64][72];
  __shared__ u16 Vt[64][72];  // V transposed: Vt[d][key]
  __shared__ u16 Ps[64][72];  // Q staged here first, then P tiles (wave-local rows)
  const int tid = threadIdx.x;
  const int lane = tid & 63;
  const int w = tid >> 6;
  const int r = lane & 15;
  const int quad = lane >> 4;
  const int qt = blockIdx.x, bh = blockIdx.y;
  const int b = bh >> 4, h = bh & 15;
  const int srow = lane;              // staging row (key/query index 0..63)
  const int sd0 = w * 16;             // staging d-offset per wave

  // stage Q tile (64 x 64) into Ps
  {
    const size_t g = ((size_t)((b * T_ + qt * 64 + srow) * H_ + h)) * D_ + sd0;
    *(bf16x8*)&Ps[srow][sd0] = *(const bf16x8*)&Qb[g];
    *(bf16x8*)&Ps[srow][sd0 + 8] = *(const bf16x8*)&Qb[g + 8];
  }
  __syncthreads();
  bf16x8 qf[2];
  qf[0] = *(const bf16x8*)&Ps[w * 16 + r][quad * 8];
  qf[1] = *(const bf16x8*)&Ps[w * 16 + r][32 + quad * 8];
  // Ps rows [w*16, w*16+16) are hereafter touched only by wave w (P tiles).

  f32x4 oacc[4];
#pragma unroll
  for (int ni = 0; ni < 4; ++ni) oacc[ni] = (f32x4){0.f, 0.f, 0.f, 0.f};
  float m_i[4], l_i[4];
#pragma unroll
  for (int j = 0; j < 4; ++j) { m_i[j] = -1e30f; l_i[j] = 0.f; }

  for (int kt = 0; kt < T_; kt += 64) {
    // stage K tile and V^T tile
    {
      const size_t g = ((size_t)((b * T_ + kt + srow) * H_ + h)) * D_ + sd0;
      bf16x8 k0 = *(const bf16x8*)&Kb[g];
      bf16x8 k1 = *(const bf16x8*)&Kb[g + 8];
      bf16x8 v0 = *(const bf16x8*)&Vb[g];
      bf16x8 v1 = *(const bf16x8*)&Vb[g + 8];
      *(bf16x8*)&Ks[srow][sd0] = k0;
      *(bf16x8*)&Ks[srow][sd0 + 8] = k1;
#pragma unroll
      for (int i = 0; i < 8; ++i) Vt[sd0 + i][srow] = (u16)v0[i];
#pragma unroll
      for (int i = 0; i < 8; ++i) Vt[sd0 + 8 + i][srow] = (u16)v1[i];
    }
    __syncthreads();

    // S = Q K^T : s[ni] covers keys [kt+ni*16, +16), rows quad*4+j
    f32x4 s[4];
#pragma unroll
    for (int ni = 0; ni < 4; ++ni) {
      s[ni] = (f32x4){0.f, 0.f, 0.f, 0.f};
#pragma unroll
      for (int kc = 0; kc < 2; ++kc) {
        bf16x8 kf = *(const bf16x8*)&Ks[ni * 16 + r][kc * 32 + quad * 8];
        s[ni] = __builtin_amdgcn_mfma_f32_16x16x32_bf16(qf[kc], kf, s[ni], 0, 0, 0);
      }
    }

    // online softmax per query row (j = row quad*4+j)
    float p[4][4];  // [ni][j]
#pragma unroll
    for (int j = 0; j < 4; ++j) {
      float s0 = s[0][j] * 0.125f, s1 = s[1][j] * 0.125f;
      float s2 = s[2][j] * 0.125f, s3 = s[3][j] * 0.125f;
      float mx = fmaxf(fmaxf(s0, s1), fmaxf(s2, s3));
      mx = fmaxf(mx, __shfl_xor(mx, 1, 64));
      mx = fmaxf(mx, __shfl_xor(mx, 2, 64));
      mx = fmaxf(mx, __shfl_xor(mx, 4, 64));
      mx = fmaxf(mx, __shfl_xor(mx, 8, 64));
      const float mn = fmaxf(m_i[j], mx);
      const float al = __expf(m_i[j] - mn);
      float p0 = __expf(s0 - mn), p1 = __expf(s1 - mn);
      float p2 = __expf(s2 - mn), p3 = __expf(s3 - mn);
      p[0][j] = p0; p[1][j] = p1; p[2][j] = p2; p[3][j] = p3;
      float sum = p0 + p1 + p2 + p3;
      sum += __shfl_xor(sum, 1, 64);
      sum += __shfl_xor(sum, 2, 64);
      sum += __shfl_xor(sum, 4, 64);
      sum += __shfl_xor(sum, 8, 64);
      l_i[j] = l_i[j] * al + sum;
      m_i[j] = mn;
#pragma unroll
      for (int ni = 0; ni < 4; ++ni) oacc[ni][j] *= al;
    }

    // write P tiles (wave-local rows): Ps[q=w*16+quad*4+j][key=ni*16+r]
#pragma unroll
    for (int j = 0; j < 4; ++j)
#pragma unroll
      for (int ni = 0; ni < 4; ++ni)
        Ps[w * 16 + quad * 4 + j][ni * 16 + r] = f2bf(p[ni][j]);

    // O += P @ V : A=P[q][key], B=Vt[d][key]
#pragma unroll
    for (int kc = 0; kc < 2; ++kc) {
      bf16x8 pf = *(const bf16x8*)&Ps[w * 16 + r][kc * 32 + quad * 8];
#pragma unroll
      for (int ni = 0; ni < 4; ++ni) {
        bf16x8 vf = *(const bf16x8*)&Vt[ni * 16 + r][kc * 32 + quad * 8];
        oacc[ni] = __builtin_amdgcn_mfma_f32_16x16x32_bf16(pf, vf, oacc[ni], 0, 0, 0);
      }
    }
    __syncthreads();
  }

  // epilogue: Y[q][d] = oacc/l ; q = qt*64 + w*16 + quad*4 + j, d = ni*16 + r
#pragma unroll
  for (int j = 0; j < 4; ++j) {
    const float inv = 1.0f / l_i[j];
    const int t = qt * 64 + w * 16 + quad * 4 + j;
    const size_t gbase = ((size_t)((b * T_ + t) * H_ + h)) * D_;
#pragma unroll
    for (int ni = 0; ni < 4; ++ni)
      Y[gbase + ni * 16 + r] = oacc[ni][j] * inv;
  }
}

extern "C" void kernel_launch(void* const* d_in, const int* in_sizes, int n_in,
                              void* d_out, int out_size, void* d_ws, size_t ws_size,
                              hipStream_t stream) {
  const float* x    = (const float*)d_in[0];
  const float* cosb = (const float*)d_in[1];
  const float* sinb = (const float*)d_in[2];
  const float* Wq   = (const float*)d_in[3];
  const float* Wk   = (const float*)d_in[4];
  const float* Wv   = (const float*)d_in[5];
  const float* Wo   = (const float*)d_in[6];
  float* out = (float*)d_out;

  const size_t NE = (size_t)B_ * T_ * C_;  // 8M elements
  // workspace (112 MB): q,k fp32 (64 MB) + qb,kb,vb bf16 (48 MB)
  float* q  = (float*)d_ws;
  float* k  = q + NE;
  u16*   qb = (u16*)(k + NE);
  u16*   kb = qb + NE;
  u16*   vb = kb + NE;
  float* y  = q;  // q fp32 dead after rope_rms; reuse as attention output

  const int M = B_ * T_;  // 8192

  dim3 gg(C_ / 128, M / 128), gb(256);
  gemm_xw<false><<<gg, gb, 0, stream>>>(x, Wq, q, M, C_, C_);
  gemm_xw<false><<<gg, gb, 0, stream>>>(x, Wk, k, M, C_, C_);
  gemm_xw<true ><<<gg, gb, 0, stream>>>(x, Wv, vb, M, C_, C_);

  dim3 rg((M * H_) / 4);
  rope_rms<<<rg, 256, 0, stream>>>(q, qb, cosb, sinb);
  rope_rms<<<rg, 256, 0, stream>>>(k, kb, cosb, sinb);

  dim3 fg(T_ / 64, B_ * H_);
  flash_mfma<<<fg, 256, 0, stream>>>(qb, kb, vb, y);

  gemm_xw<false><<<gg, gb, 0, stream>>>(y, Wo, out, M, C_, C_);
}

// Round 7
// 523.689 us; speedup vs baseline: 5.4945x; 1.1031x over previous
//
#include <hip/hip_runtime.h>

#define B_ 4
#define T_ 2048
#define C_ 1024
#define H_ 16
#define D_ 64
#define EPS_ 1.1920929e-07f

typedef __attribute__((ext_vector_type(8))) short bf16x8;
typedef __attribute__((ext_vector_type(4))) float f32x4;
typedef unsigned short u16;

__device__ inline u16 f2bf(float f) {
  unsigned u = __float_as_uint(f);
  unsigned r = (u + 0x7fffu + ((u >> 16) & 1u)) >> 16;
  return (u16)r;
}
__device__ inline float bf2f(u16 v) { return __uint_as_float(((unsigned)v) << 16); }

// ---------------- f32 -> bf16 conversion ----------------
__global__ __launch_bounds__(256) void cvt_bf16(const float* __restrict__ src,
                                                u16* __restrict__ dst, int n) {
  const int i = (blockIdx.x * 256 + threadIdx.x) * 4;
  if (i < n) {
    float4 v = *(const float4*)&src[i];
    ushort4 o;
    o.x = f2bf(v.x); o.y = f2bf(v.y); o.z = f2bf(v.z); o.w = f2bf(v.w);
    *(ushort4*)&dst[i] = o;
  }
}

// ---------------- bf16 MFMA GEMM: Y = X @ W^T ----------------
// X: (M,K) bf16, W: (N,K) bf16, Y: (M,N) f32 or bf16.
// 128x128 tile, BK=64, 256 threads = 4 waves (2x2), each wave 64x64 out.
// Register round-trip staging (proven round 5; global_load_lds kills container).
template <bool BF16OUT>
__global__ __launch_bounds__(256) void gemm_bf16(const u16* __restrict__ X,
                                                 const u16* __restrict__ W,
                                                 void* __restrict__ Yv,
                                                 int M, int N, int K) {
  __shared__ short As[128 * 64];
  __shared__ short Bs[128 * 64];
  const int tid = threadIdx.x;
  const int lane = tid & 63;
  const int w = tid >> 6;
  const int wr = w >> 1, wc = w & 1;
  const int m0 = blockIdx.y * 128, n0 = blockIdx.x * 128;
  const int srow = lane >> 3;
  const int scol = (lane & 7) * 8;

  f32x4 acc[4][4];
#pragma unroll
  for (int mi = 0; mi < 4; ++mi)
#pragma unroll
    for (int ni = 0; ni < 4; ++ni)
      acc[mi][ni] = (f32x4){0.f, 0.f, 0.f, 0.f};

  const int r = lane & 15;
  const int quad = lane >> 4;

  for (int kt = 0; kt < K; kt += 64) {
#pragma unroll
    for (int i = 0; i < 4; ++i) {
      const int row = w * 32 + i * 8 + srow;
      bf16x8 av = *(const bf16x8*)&X[(size_t)(m0 + row) * K + kt + scol];
      bf16x8 bv = *(const bf16x8*)&W[(size_t)(n0 + row) * K + kt + scol];
      *(bf16x8*)&As[row * 64 + scol] = av;
      *(bf16x8*)&Bs[row * 64 + scol] = bv;
    }
    __syncthreads();

#pragma unroll
    for (int kc = 0; kc < 2; ++kc) {
      const int ko = kc * 32 + quad * 8;
      bf16x8 a[4], b[4];
#pragma unroll
      for (int mi = 0; mi < 4; ++mi)
        a[mi] = *(const bf16x8*)&As[(wr * 64 + mi * 16 + r) * 64 + ko];
#pragma unroll
      for (int ni = 0; ni < 4; ++ni)
        b[ni] = *(const bf16x8*)&Bs[(wc * 64 + ni * 16 + r) * 64 + ko];
#pragma unroll
      for (int mi = 0; mi < 4; ++mi)
#pragma unroll
        for (int ni = 0; ni < 4; ++ni)
          acc[mi][ni] = __builtin_amdgcn_mfma_f32_16x16x32_bf16(a[mi], b[ni], acc[mi][ni], 0, 0, 0);
    }
    __syncthreads();
  }

  // epilogue: C/D layout col=lane&15, row=quad*4+j (verified m89/m91)
#pragma unroll
  for (int mi = 0; mi < 4; ++mi)
#pragma unroll
    for (int ni = 0; ni < 4; ++ni) {
      const int gc = n0 + wc * 64 + ni * 16 + r;
#pragma unroll
      for (int j = 0; j < 4; ++j) {
        const int gr = m0 + wr * 64 + mi * 16 + quad * 4 + j;
        if (BF16OUT)
          ((u16*)Yv)[(size_t)gr * N + gc] = f2bf(acc[mi][ni][j]);
        else
          ((float*)Yv)[(size_t)gr * N + gc] = acc[mi][ni][j];
      }
    }
}

// ---------------- fused RoPE + RMSNorm: bf16 in-place ----------------
__global__ __launch_bounds__(256) void rope_rms(u16* __restrict__ buf,
                                                const float* __restrict__ cs,
                                                const float* __restrict__ sn) {
  const int row = blockIdx.x * 4 + (threadIdx.x >> 6);
  const int lane = threadIdx.x & 63;
  const int t = (row / H_) % T_;
  const size_t base = (size_t)row * 64;
  float v = bf2f(buf[base + lane]);
  float p = __shfl_xor(v, 32, 64);
  const int idx = lane & 31;
  const float c = cs[t * 32 + idx], s = sn[t * 32 + idx];
  float o = (lane < 32) ? (v * c + p * s) : (v * c - p * s);
  float sq = o * o;
#pragma unroll
  for (int m = 1; m < 64; m <<= 1) sq += __shfl_xor(sq, m, 64);
  const float r = rsqrtf(sq * (1.0f / 64.0f) + EPS_);
  buf[base + lane] = f2bf(o * r);
}

// ---------------- MFMA flash attention (unchanged from round 6) ----------------
__global__ __launch_bounds__(256) void flash_mfma(const u16* __restrict__ Qb,
                                                  const u16* __restrict__ Kb,
                                                  const u16* __restrict__ Vb,
                                                  float* __restrict__ Y) {
  __shared__ u16 Ks[64][72];
  __shared__ u16 Vt[64][72];
  __shared__ u16 Ps[64][72];
  const int tid = threadIdx.x;
  const int lane = tid & 63;
  const int w = tid >> 6;
  const int r = lane & 15;
  const int quad = lane >> 4;
  const int qt = blockIdx.x, bh = blockIdx.y;
  const int b = bh >> 4, h = bh & 15;
  const int srow = lane;
  const int sd0 = w * 16;

  {
    const size_t g = ((size_t)((b * T_ + qt * 64 + srow) * H_ + h)) * D_ + sd0;
    *(bf16x8*)&Ps[srow][sd0] = *(const bf16x8*)&Qb[g];
    *(bf16x8*)&Ps[srow][sd0 + 8] = *(const bf16x8*)&Qb[g + 8];
  }
  __syncthreads();
  bf16x8 qf[2];
  qf[0] = *(const bf16x8*)&Ps[w * 16 + r][quad * 8];
  qf[1] = *(const bf16x8*)&Ps[w * 16 + r][32 + quad * 8];

  f32x4 oacc[4];
#pragma unroll
  for (int ni = 0; ni < 4; ++ni) oacc[ni] = (f32x4){0.f, 0.f, 0.f, 0.f};
  float m_i[4], l_i[4];
#pragma unroll
  for (int j = 0; j < 4; ++j) { m_i[j] = -1e30f; l_i[j] = 0.f; }

  for (int kt = 0; kt < T_; kt += 64) {
    {
      const size_t g = ((size_t)((b * T_ + kt + srow) * H_ + h)) * D_ + sd0;
      bf16x8 k0 = *(const bf16x8*)&Kb[g];
      bf16x8 k1 = *(const bf16x8*)&Kb[g + 8];
      bf16x8 v0 = *(const bf16x8*)&Vb[g];
      bf16x8 v1 = *(const bf16x8*)&Vb[g + 8];
      *(bf16x8*)&Ks[srow][sd0] = k0;
      *(bf16x8*)&Ks[srow][sd0 + 8] = k1;
#pragma unroll
      for (int i = 0; i < 8; ++i) Vt[sd0 + i][srow] = (u16)v0[i];
#pragma unroll
      for (int i = 0; i < 8; ++i) Vt[sd0 + 8 + i][srow] = (u16)v1[i];
    }
    __syncthreads();

    f32x4 s[4];
#pragma unroll
    for (int ni = 0; ni < 4; ++ni) {
      s[ni] = (f32x4){0.f, 0.f, 0.f, 0.f};
#pragma unroll
      for (int kc = 0; kc < 2; ++kc) {
        bf16x8 kf = *(const bf16x8*)&Ks[ni * 16 + r][kc * 32 + quad * 8];
        s[ni] = __builtin_amdgcn_mfma_f32_16x16x32_bf16(qf[kc], kf, s[ni], 0, 0, 0);
      }
    }

    float p[4][4];
#pragma unroll
    for (int j = 0; j < 4; ++j) {
      float s0 = s[0][j] * 0.125f, s1 = s[1][j] * 0.125f;
      float s2 = s[2][j] * 0.125f, s3 = s[3][j] * 0.125f;
      float mx = fmaxf(fmaxf(s0, s1), fmaxf(s2, s3));
      mx = fmaxf(mx, __shfl_xor(mx, 1, 64));
      mx = fmaxf(mx, __shfl_xor(mx, 2, 64));
      mx = fmaxf(mx, __shfl_xor(mx, 4, 64));
      mx = fmaxf(mx, __shfl_xor(mx, 8, 64));
      const float mn = fmaxf(m_i[j], mx);
      const float al = __expf(m_i[j] - mn);
      float p0 = __expf(s0 - mn), p1 = __expf(s1 - mn);
      float p2 = __expf(s2 - mn), p3 = __expf(s3 - mn);
      p[0][j] = p0; p[1][j] = p1; p[2][j] = p2; p[3][j] = p3;
      float sum = p0 + p1 + p2 + p3;
      sum += __shfl_xor(sum, 1, 64);
      sum += __shfl_xor(sum, 2, 64);
      sum += __shfl_xor(sum, 4, 64);
      sum += __shfl_xor(sum, 8, 64);
      l_i[j] = l_i[j] * al + sum;
      m_i[j] = mn;
#pragma unroll
      for (int ni = 0; ni < 4; ++ni) oacc[ni][j] *= al;
    }

#pragma unroll
    for (int j = 0; j < 4; ++j)
#pragma unroll
      for (int ni = 0; ni < 4; ++ni)
        Ps[w * 16 + quad * 4 + j][ni * 16 + r] = f2bf(p[ni][j]);

#pragma unroll
    for (int kc = 0; kc < 2; ++kc) {
      bf16x8 pf = *(const bf16x8*)&Ps[w * 16 + r][kc * 32 + quad * 8];
#pragma unroll
      for (int ni = 0; ni < 4; ++ni) {
        bf16x8 vf = *(const bf16x8*)&Vt[ni * 16 + r][kc * 32 + quad * 8];
        oacc[ni] = __builtin_amdgcn_mfma_f32_16x16x32_bf16(pf, vf, oacc[ni], 0, 0, 0);
      }
    }
    __syncthreads();
  }

#pragma unroll
  for (int j = 0; j < 4; ++j) {
    const float inv = 1.0f / l_i[j];
    const int t = qt * 64 + w * 16 + quad * 4 + j;
    const size_t gbase = ((size_t)((b * T_ + t) * H_ + h)) * D_;
#pragma unroll
    for (int ni = 0; ni < 4; ++ni)
      Y[gbase + ni * 16 + r] = oacc[ni][j] * inv;
  }
}

extern "C" void kernel_launch(void* const* d_in, const int* in_sizes, int n_in,
                              void* d_out, int out_size, void* d_ws, size_t ws_size,
                              hipStream_t stream) {
  const float* x    = (const float*)d_in[0];
  const float* cosb = (const float*)d_in[1];
  const float* sinb = (const float*)d_in[2];
  const float* Wq   = (const float*)d_in[3];
  const float* Wk   = (const float*)d_in[4];
  const float* Wv   = (const float*)d_in[5];
  const float* Wo   = (const float*)d_in[6];
  float* out = (float*)d_out;

  const size_t NE = (size_t)B_ * T_ * C_;  // 8M elements
  const int CC = C_ * C_;                  // 1M elements
  // workspace (~104 MB): qb,kb,vb,xb bf16 (64 MB) + weights bf16 (8 MB) + y fp32 (32 MB)
  u16* qb  = (u16*)d_ws;
  u16* kb  = qb + NE;
  u16* vb  = kb + NE;
  u16* xb  = vb + NE;
  u16* wqb = xb + NE;
  u16* wkb = wqb + CC;
  u16* wvb = wkb + CC;
  u16* wob = wvb + CC;
  float* y = (float*)(wob + CC);
  u16* yb  = xb;  // xb dead after QKV GEMMs

  const int M = B_ * T_;  // 8192

  cvt_bf16<<<(int)(NE / 1024), 256, 0, stream>>>(x, xb, (int)NE);
  cvt_bf16<<<CC / 1024, 256, 0, stream>>>(Wq, wqb, CC);
  cvt_bf16<<<CC / 1024, 256, 0, stream>>>(Wk, wkb, CC);
  cvt_bf16<<<CC / 1024, 256, 0, stream>>>(Wv, wvb, CC);
  cvt_bf16<<<CC / 1024, 256, 0, stream>>>(Wo, wob, CC);

  dim3 gg(C_ / 128, M / 128), gb(256);
  gemm_bf16<true><<<gg, gb, 0, stream>>>(xb, wqb, qb, M, C_, C_);
  gemm_bf16<true><<<gg, gb, 0, stream>>>(xb, wkb, kb, M, C_, C_);
  gemm_bf16<true><<<gg, gb, 0, stream>>>(xb, wvb, vb, M, C_, C_);

  dim3 rg((M * H_) / 4);
  rope_rms<<<rg, 256, 0, stream>>>(qb, cosb, sinb);
  rope_rms<<<rg, 256, 0, stream>>>(kb, cosb, sinb);

  dim3 fg(T_ / 64, B_ * H_);
  flash_mfma<<<fg, 256, 0, stream>>>(qb, kb, vb, y);

  cvt_bf16<<<(int)(NE / 1024), 256, 0, stream>>>(y, yb, (int)NE);
  gemm_bf16<false><<<gg, gb, 0, stream>>>(yb, wob, out, M, C_, C_);
}

// Round 8
// 460.358 us; speedup vs baseline: 6.2504x; 1.1376x over previous
//
#include <hip/hip_runtime.h>

#define B_ 4
#define T_ 2048
#define C_ 1024
#define H_ 16
#define D_ 64
#define EPS_ 1.1920929e-07f

typedef __attribute__((ext_vector_type(8))) short bf16x8;
typedef __attribute__((ext_vector_type(4))) float f32x4;
typedef unsigned short u16;

__device__ inline u16 f2bf(float f) {
  unsigned u = __float_as_uint(f);
  unsigned r = (u + 0x7fffu + ((u >> 16) & 1u)) >> 16;
  return (u16)r;
}

// ---------------- f32 -> bf16 conversion ----------------
__global__ __launch_bounds__(256) void cvt_bf16(const float* __restrict__ src,
                                                u16* __restrict__ dst, int n) {
  const int i = (blockIdx.x * 256 + threadIdx.x) * 4;
  if (i < n) {
    float4 v = *(const float4*)&src[i];
    ushort4 o;
    o.x = f2bf(v.x); o.y = f2bf(v.y); o.z = f2bf(v.z); o.w = f2bf(v.w);
    *(ushort4*)&dst[i] = o;
  }
}

// ---------------- bf16 MFMA GEMM: Y = X @ W^T ----------------
// MODE 0: fp32 out. 1: bf16 out. 2: fused rope+rms, bf16 out, *0.125 (Q).
// 3: fused rope+rms, bf16 out (K).
// 128x128 tile, BK=64, 4 waves (2x2). Software-pipelined global->reg prefetch.
template <int MODE>
__global__ __launch_bounds__(256) void gemm_bf16(const u16* __restrict__ X,
                                                 const u16* __restrict__ W,
                                                 void* __restrict__ Yv,
                                                 const float* __restrict__ cs,
                                                 const float* __restrict__ sn,
                                                 int M, int N, int K) {
  __shared__ short As[128 * 64];
  __shared__ short Bs[128 * 64];
  const int tid = threadIdx.x;
  const int lane = tid & 63;
  const int w = tid >> 6;
  const int wr = w >> 1, wc = w & 1;
  const int m0 = blockIdx.y * 128, n0 = blockIdx.x * 128;
  const int srow = lane >> 3;
  const int scol = (lane & 7) * 8;

  f32x4 acc[4][4];
#pragma unroll
  for (int mi = 0; mi < 4; ++mi)
#pragma unroll
    for (int ni = 0; ni < 4; ++ni)
      acc[mi][ni] = (f32x4){0.f, 0.f, 0.f, 0.f};

  const int r = lane & 15;
  const int quad = lane >> 4;

  // prologue: prefetch tile kt=0 into registers
  bf16x8 av[4], bv[4];
#pragma unroll
  for (int i = 0; i < 4; ++i) {
    const int row = w * 32 + i * 8 + srow;
    av[i] = *(const bf16x8*)&X[(size_t)(m0 + row) * K + scol];
    bv[i] = *(const bf16x8*)&W[(size_t)(n0 + row) * K + scol];
  }

  for (int kt = 0; kt < K; kt += 64) {
#pragma unroll
    for (int i = 0; i < 4; ++i) {
      const int row = w * 32 + i * 8 + srow;
      *(bf16x8*)&As[row * 64 + scol] = av[i];
      *(bf16x8*)&Bs[row * 64 + scol] = bv[i];
    }
    __syncthreads();
    if (kt + 64 < K) {  // prefetch next tile (overlaps with MFMA below)
#pragma unroll
      for (int i = 0; i < 4; ++i) {
        const int row = w * 32 + i * 8 + srow;
        av[i] = *(const bf16x8*)&X[(size_t)(m0 + row) * K + kt + 64 + scol];
        bv[i] = *(const bf16x8*)&W[(size_t)(n0 + row) * K + kt + 64 + scol];
      }
    }
#pragma unroll
    for (int kc = 0; kc < 2; ++kc) {
      const int ko = kc * 32 + quad * 8;
      bf16x8 a[4], b[4];
#pragma unroll
      for (int mi = 0; mi < 4; ++mi)
        a[mi] = *(const bf16x8*)&As[(wr * 64 + mi * 16 + r) * 64 + ko];
#pragma unroll
      for (int ni = 0; ni < 4; ++ni)
        b[ni] = *(const bf16x8*)&Bs[(wc * 64 + ni * 16 + r) * 64 + ko];
#pragma unroll
      for (int mi = 0; mi < 4; ++mi)
#pragma unroll
        for (int ni = 0; ni < 4; ++ni)
          acc[mi][ni] = __builtin_amdgcn_mfma_f32_16x16x32_bf16(a[mi], b[ni], acc[mi][ni], 0, 0, 0);
    }
    __syncthreads();
  }

  // epilogue: C/D layout col=lane&15, row=quad*4+j
  if (MODE >= 2) {
    // fused RoPE + RMSNorm: wave's 64-col slice (n0+wc*64..+64) is one head;
    // d = ni*16+r; pair (d, d+32) = (ni, ni+2) in-lane; rms over r-lanes+ni.
    u16* Yp = (u16*)Yv;
#pragma unroll
    for (int mi = 0; mi < 4; ++mi)
#pragma unroll
      for (int j = 0; j < 4; ++j) {
        const int gr = m0 + wr * 64 + mi * 16 + quad * 4 + j;
        const int t = gr & (T_ - 1);
        float o[4];
#pragma unroll
        for (int ni = 0; ni < 2; ++ni) {
          const float c = cs[t * 32 + ni * 16 + r];
          const float s = sn[t * 32 + ni * 16 + r];
          const float x1 = acc[mi][ni][j], x2 = acc[mi][ni + 2][j];
          o[ni]     = x1 * c + x2 * s;
          o[ni + 2] = x2 * c - x1 * s;
        }
        float sq = o[0] * o[0] + o[1] * o[1] + o[2] * o[2] + o[3] * o[3];
        sq += __shfl_xor(sq, 1, 64);
        sq += __shfl_xor(sq, 2, 64);
        sq += __shfl_xor(sq, 4, 64);
        sq += __shfl_xor(sq, 8, 64);
        float rn = rsqrtf(sq * (1.0f / 64.0f) + EPS_);
        if (MODE == 2) rn *= 0.125f;  // fold attention scale into Q
#pragma unroll
        for (int ni = 0; ni < 4; ++ni)
          Yp[(size_t)gr * N + n0 + wc * 64 + ni * 16 + r] = f2bf(o[ni] * rn);
      }
  } else {
#pragma unroll
    for (int mi = 0; mi < 4; ++mi)
#pragma unroll
      for (int ni = 0; ni < 4; ++ni) {
        const int gc = n0 + wc * 64 + ni * 16 + r;
#pragma unroll
        for (int j = 0; j < 4; ++j) {
          const int gr = m0 + wr * 64 + mi * 16 + quad * 4 + j;
          if (MODE == 1)
            ((u16*)Yv)[(size_t)gr * N + gc] = f2bf(acc[mi][ni][j]);
          else
            ((float*)Yv)[(size_t)gr * N + gc] = acc[mi][ni][j];
        }
      }
  }
}

// ---------------- MFMA flash attention, 128 queries/block ----------------
// Q,K,V bf16 (B,T,H,D); Q pre-scaled by 0.125. Output bf16.
// grid=(T/128, B*H), block=256 (4 waves); wave w owns queries [w*32, w*32+32).
__global__ __launch_bounds__(256) void flash_mfma(const u16* __restrict__ Qb,
                                                  const u16* __restrict__ Kb,
                                                  const u16* __restrict__ Vb,
                                                  u16* __restrict__ Yb) {
  __shared__ u16 Ks[64][72];
  __shared__ u16 Vt[64][72];   // V transposed: Vt[d][key]
  __shared__ u16 Ps[128][72];  // Q staged here first, then P tiles (wave-local rows)
  const int tid = threadIdx.x;
  const int lane = tid & 63;
  const int w = tid >> 6;
  const int r = lane & 15;
  const int quad = lane >> 4;
  const int qt = blockIdx.x, bh = blockIdx.y;
  const int b = bh >> 4, h = bh & 15;
  const int srow = lane;       // K/V staging row
  const int sd0 = w * 16;      // K/V staging d-offset per wave

  // stage Q tile (128 x 64): 2 threads per row, 32 elems each
  {
    const int row = tid >> 1, half = tid & 1;
    const size_t g = ((size_t)((b * T_ + qt * 128 + row) * H_ + h)) * D_ + half * 32;
    *(bf16x8*)&Ps[row][half * 32]      = *(const bf16x8*)&Qb[g];
    *(bf16x8*)&Ps[row][half * 32 + 8]  = *(const bf16x8*)&Qb[g + 8];
    *(bf16x8*)&Ps[row][half * 32 + 16] = *(const bf16x8*)&Qb[g + 16];
    *(bf16x8*)&Ps[row][half * 32 + 24] = *(const bf16x8*)&Qb[g + 24];
  }
  __syncthreads();
  bf16x8 qf[2][2];
#pragma unroll
  for (int qg = 0; qg < 2; ++qg)
#pragma unroll
    for (int kc = 0; kc < 2; ++kc)
      qf[qg][kc] = *(const bf16x8*)&Ps[w * 32 + qg * 16 + r][kc * 32 + quad * 8];
  // Ps rows [w*32, w*32+32) hereafter touched only by wave w (P tiles).

  f32x4 oacc[2][4];
#pragma unroll
  for (int qg = 0; qg < 2; ++qg)
#pragma unroll
    for (int ni = 0; ni < 4; ++ni) oacc[qg][ni] = (f32x4){0.f, 0.f, 0.f, 0.f};
  float m_i[2][4], l_i[2][4];
#pragma unroll
  for (int qg = 0; qg < 2; ++qg)
#pragma unroll
    for (int j = 0; j < 4; ++j) { m_i[qg][j] = -1e30f; l_i[qg][j] = 0.f; }

  // prefetch K/V tile 0
  bf16x8 k0, k1, v0, v1;
  {
    const size_t g = ((size_t)((b * T_ + srow) * H_ + h)) * D_ + sd0;
    k0 = *(const bf16x8*)&Kb[g];
    k1 = *(const bf16x8*)&Kb[g + 8];
    v0 = *(const bf16x8*)&Vb[g];
    v1 = *(const bf16x8*)&Vb[g + 8];
  }

  for (int kt = 0; kt < T_; kt += 64) {
    // write staged regs to LDS
    *(bf16x8*)&Ks[srow][sd0] = k0;
    *(bf16x8*)&Ks[srow][sd0 + 8] = k1;
#pragma unroll
    for (int i = 0; i < 8; ++i) Vt[sd0 + i][srow] = (u16)v0[i];
#pragma unroll
    for (int i = 0; i < 8; ++i) Vt[sd0 + 8 + i][srow] = (u16)v1[i];
    __syncthreads();
    if (kt + 64 < T_) {  // prefetch next tile (overlaps with compute)
      const size_t g = ((size_t)((b * T_ + kt + 64 + srow) * H_ + h)) * D_ + sd0;
      k0 = *(const bf16x8*)&Kb[g];
      k1 = *(const bf16x8*)&Kb[g + 8];
      v0 = *(const bf16x8*)&Vb[g];
      v1 = *(const bf16x8*)&Vb[g + 8];
    }

#pragma unroll
    for (int qg = 0; qg < 2; ++qg) {
      // S = Q K^T (scale pre-folded into Q)
      f32x4 s[4];
#pragma unroll
      for (int ni = 0; ni < 4; ++ni) {
        s[ni] = (f32x4){0.f, 0.f, 0.f, 0.f};
#pragma unroll
        for (int kc = 0; kc < 2; ++kc) {
          bf16x8 kf = *(const bf16x8*)&Ks[ni * 16 + r][kc * 32 + quad * 8];
          s[ni] = __builtin_amdgcn_mfma_f32_16x16x32_bf16(qf[qg][kc], kf, s[ni], 0, 0, 0);
        }
      }
      // online softmax; rows quad*4+j
#pragma unroll
      for (int j = 0; j < 4; ++j) {
        float s0 = s[0][j], s1 = s[1][j], s2 = s[2][j], s3 = s[3][j];
        float mx = fmaxf(fmaxf(s0, s1), fmaxf(s2, s3));
        mx = fmaxf(mx, __shfl_xor(mx, 1, 64));
        mx = fmaxf(mx, __shfl_xor(mx, 2, 64));
        mx = fmaxf(mx, __shfl_xor(mx, 4, 64));
        mx = fmaxf(mx, __shfl_xor(mx, 8, 64));
        const float mn = fmaxf(m_i[qg][j], mx);
        const float al = __expf(m_i[qg][j] - mn);
        float p0 = __expf(s0 - mn), p1 = __expf(s1 - mn);
        float p2 = __expf(s2 - mn), p3 = __expf(s3 - mn);
        float sum = p0 + p1 + p2 + p3;
        sum += __shfl_xor(sum, 1, 64);
        sum += __shfl_xor(sum, 2, 64);
        sum += __shfl_xor(sum, 4, 64);
        sum += __shfl_xor(sum, 8, 64);
        l_i[qg][j] = l_i[qg][j] * al + sum;
        m_i[qg][j] = mn;
#pragma unroll
        for (int ni = 0; ni < 4; ++ni) oacc[qg][ni][j] *= al;
        const int prow = w * 32 + qg * 16 + quad * 4 + j;
        Ps[prow][r]      = f2bf(p0);
        Ps[prow][16 + r] = f2bf(p1);
        Ps[prow][32 + r] = f2bf(p2);
        Ps[prow][48 + r] = f2bf(p3);
      }
      // O += P @ V
#pragma unroll
      for (int kc = 0; kc < 2; ++kc) {
        bf16x8 pf = *(const bf16x8*)&Ps[w * 32 + qg * 16 + r][kc * 32 + quad * 8];
#pragma unroll
        for (int ni = 0; ni < 4; ++ni) {
          bf16x8 vf = *(const bf16x8*)&Vt[ni * 16 + r][kc * 32 + quad * 8];
          oacc[qg][ni] = __builtin_amdgcn_mfma_f32_16x16x32_bf16(pf, vf, oacc[qg][ni], 0, 0, 0);
        }
      }
    }
    __syncthreads();
  }

  // epilogue: bf16 out
#pragma unroll
  for (int qg = 0; qg < 2; ++qg)
#pragma unroll
    for (int j = 0; j < 4; ++j) {
      const float inv = 1.0f / l_i[qg][j];
      const int t = qt * 128 + w * 32 + qg * 16 + quad * 4 + j;
      const size_t gbase = ((size_t)((b * T_ + t) * H_ + h)) * D_;
#pragma unroll
      for (int ni = 0; ni < 4; ++ni)
        Yb[gbase + ni * 16 + r] = f2bf(oacc[qg][ni][j] * inv);
    }
}

extern "C" void kernel_launch(void* const* d_in, const int* in_sizes, int n_in,
                              void* d_out, int out_size, void* d_ws, size_t ws_size,
                              hipStream_t stream) {
  const float* x    = (const float*)d_in[0];
  const float* cosb = (const float*)d_in[1];
  const float* sinb = (const float*)d_in[2];
  const float* Wq   = (const float*)d_in[3];
  const float* Wk   = (const float*)d_in[4];
  const float* Wv   = (const float*)d_in[5];
  const float* Wo   = (const float*)d_in[6];
  float* out = (float*)d_out;

  const size_t NE = (size_t)B_ * T_ * C_;  // 8M elements
  const int CC = C_ * C_;                  // 1M elements
  // workspace (~88 MB): xb,qb,kb,vb,yb bf16 (80 MB) + weights bf16 (8 MB)
  u16* xb  = (u16*)d_ws;
  u16* qb  = xb + NE;
  u16* kb  = qb + NE;
  u16* vb  = kb + NE;
  u16* yb  = xb;  // xb dead after QKV GEMMs; reuse for attention output
  u16* wqb = vb + NE;
  u16* wkb = wqb + CC;
  u16* wvb = wkb + CC;
  u16* wob = wvb + CC;

  const int M = B_ * T_;  // 8192

  cvt_bf16<<<(int)(NE / 1024), 256, 0, stream>>>(x, xb, (int)NE);
  cvt_bf16<<<CC / 1024, 256, 0, stream>>>(Wq, wqb, CC);
  cvt_bf16<<<CC / 1024, 256, 0, stream>>>(Wk, wkb, CC);
  cvt_bf16<<<CC / 1024, 256, 0, stream>>>(Wv, wvb, CC);
  cvt_bf16<<<CC / 1024, 256, 0, stream>>>(Wo, wob, CC);

  dim3 gg(C_ / 128, M / 128), gb(256);
  gemm_bf16<2><<<gg, gb, 0, stream>>>(xb, wqb, qb, cosb, sinb, M, C_, C_);
  gemm_bf16<3><<<gg, gb, 0, stream>>>(xb, wkb, kb, cosb, sinb, M, C_, C_);
  gemm_bf16<1><<<gg, gb, 0, stream>>>(xb, wvb, vb, cosb, sinb, M, C_, C_);

  dim3 fg(T_ / 128, B_ * H_);
  flash_mfma<<<fg, 256, 0, stream>>>(qb, kb, vb, yb);

  gemm_bf16<0><<<gg, gb, 0, stream>>>(yb, wob, out, cosb, sinb, M, C_, C_);
}

// Round 9
// 337.227 us; speedup vs baseline: 8.5326x; 1.3651x over previous
//
#include <hip/hip_runtime.h>

#define B_ 4
#define T_ 2048
#define C_ 1024
#define H_ 16
#define D_ 64
#define EPS_ 1.1920929e-07f

typedef __attribute__((ext_vector_type(8))) short bf16x8;
typedef __attribute__((ext_vector_type(4))) float f32x4;
typedef unsigned short u16;
typedef unsigned int u32;

__device__ inline u16 f2bf(float f) {
  unsigned u = __float_as_uint(f);
  unsigned r = (u + 0x7fffu + ((u >> 16) & 1u)) >> 16;
  return (u16)r;
}

// ---------------- f32 -> bf16 conversion (x) ----------------
__global__ __launch_bounds__(256) void cvt_bf16(const float* __restrict__ src,
                                                u16* __restrict__ dst, int n) {
  const int i = (blockIdx.x * 256 + threadIdx.x) * 4;
  if (i < n) {
    float4 v = *(const float4*)&src[i];
    ushort4 o;
    o.x = f2bf(v.x); o.y = f2bf(v.y); o.z = f2bf(v.z); o.w = f2bf(v.w);
    *(ushort4*)&dst[i] = o;
  }
}

// ---------------- all 4 weights in one launch ----------------
__global__ __launch_bounds__(256) void cvt_weights(const float* __restrict__ wq,
                                                   const float* __restrict__ wk,
                                                   const float* __restrict__ wv,
                                                   const float* __restrict__ wo,
                                                   u16* __restrict__ wqkv,
                                                   u16* __restrict__ wob, int n) {
  const int i = (blockIdx.x * 256 + threadIdx.x) * 4;
  const int t = blockIdx.y;
  const float* src = (t == 0) ? wq : (t == 1) ? wk : (t == 2) ? wv : wo;
  u16* dst = (t == 3) ? wob : (wqkv + (size_t)t * n);
  if (i < n) {
    float4 v = *(const float4*)&src[i];
    ushort4 o;
    o.x = f2bf(v.x); o.y = f2bf(v.y); o.z = f2bf(v.z); o.w = f2bf(v.w);
    *(ushort4*)&dst[i] = o;
  }
}

// ---------------- fused QKV GEMM: [Q|K|V] = X @ Wqkv^T + epilogues ----------------
// X: (M,1024) bf16, Wqkv: (3072,1024) bf16. 128x128 tile, BK=64, 4 waves.
// blockIdx.x: 0..7 -> Q (rope+rms, *0.125), 8..15 -> K (rope+rms), 16..23 -> V.
__global__ __launch_bounds__(256) void gemm_qkv(const u16* __restrict__ X,
                                                const u16* __restrict__ W,
                                                u16* __restrict__ qb,
                                                u16* __restrict__ kb,
                                                u16* __restrict__ vb,
                                                const float* __restrict__ cs,
                                                const float* __restrict__ sn,
                                                int M, int K) {
  __shared__ short As[128 * 64];
  __shared__ short Bs[128 * 64];
  const int tid = threadIdx.x;
  const int lane = tid & 63;
  const int w = tid >> 6;
  const int wr = w >> 1, wc = w & 1;
  const int m0 = blockIdx.y * 128, n0 = blockIdx.x * 128;
  const int srow = lane >> 3;
  const int scol = (lane & 7) * 8;

  f32x4 acc[4][4];
#pragma unroll
  for (int mi = 0; mi < 4; ++mi)
#pragma unroll
    for (int ni = 0; ni < 4; ++ni)
      acc[mi][ni] = (f32x4){0.f, 0.f, 0.f, 0.f};

  const int r = lane & 15;
  const int quad = lane >> 4;

  bf16x8 av[4], bv[4];
#pragma unroll
  for (int i = 0; i < 4; ++i) {
    const int row = w * 32 + i * 8 + srow;
    av[i] = *(const bf16x8*)&X[(size_t)(m0 + row) * K + scol];
    bv[i] = *(const bf16x8*)&W[(size_t)(n0 + row) * K + scol];
  }

  for (int kt = 0; kt < K; kt += 64) {
#pragma unroll
    for (int i = 0; i < 4; ++i) {
      const int row = w * 32 + i * 8 + srow;
      *(bf16x8*)&As[row * 64 + scol] = av[i];
      *(bf16x8*)&Bs[row * 64 + scol] = bv[i];
    }
    __syncthreads();
    if (kt + 64 < K) {
#pragma unroll
      for (int i = 0; i < 4; ++i) {
        const int row = w * 32 + i * 8 + srow;
        av[i] = *(const bf16x8*)&X[(size_t)(m0 + row) * K + kt + 64 + scol];
        bv[i] = *(const bf16x8*)&W[(size_t)(n0 + row) * K + kt + 64 + scol];
      }
    }
#pragma unroll
    for (int kc = 0; kc < 2; ++kc) {
      const int ko = kc * 32 + quad * 8;
      bf16x8 a[4], b[4];
#pragma unroll
      for (int mi = 0; mi < 4; ++mi)
        a[mi] = *(const bf16x8*)&As[(wr * 64 + mi * 16 + r) * 64 + ko];
#pragma unroll
      for (int ni = 0; ni < 4; ++ni)
        b[ni] = *(const bf16x8*)&Bs[(wc * 64 + ni * 16 + r) * 64 + ko];
#pragma unroll
      for (int mi = 0; mi < 4; ++mi)
#pragma unroll
        for (int ni = 0; ni < 4; ++ni)
          acc[mi][ni] = __builtin_amdgcn_mfma_f32_16x16x32_bf16(a[mi], b[ni], acc[mi][ni], 0, 0, 0);
    }
    __syncthreads();
  }

  const int which = blockIdx.x >> 3;             // 0=Q 1=K 2=V
  const int c0 = (blockIdx.x & 7) * 128 + wc * 64;  // column within tensor (one head/wave)
  u16* dst = (which == 0) ? qb : (which == 1) ? kb : vb;

  if (which < 2) {
    // fused RoPE + RMSNorm; d = ni*16+r, pair (d,d+32) = (ni,ni+2) in-lane
#pragma unroll
    for (int mi = 0; mi < 4; ++mi)
#pragma unroll
      for (int j = 0; j < 4; ++j) {
        const int gr = m0 + wr * 64 + mi * 16 + quad * 4 + j;
        const int t = gr & (T_ - 1);
        float o[4];
#pragma unroll
        for (int ni = 0; ni < 2; ++ni) {
          const float c = cs[t * 32 + ni * 16 + r];
          const float s = sn[t * 32 + ni * 16 + r];
          const float x1 = acc[mi][ni][j], x2 = acc[mi][ni + 2][j];
          o[ni]     = x1 * c + x2 * s;
          o[ni + 2] = x2 * c - x1 * s;
        }
        float sq = o[0] * o[0] + o[1] * o[1] + o[2] * o[2] + o[3] * o[3];
        sq += __shfl_xor(sq, 1, 64);
        sq += __shfl_xor(sq, 2, 64);
        sq += __shfl_xor(sq, 4, 64);
        sq += __shfl_xor(sq, 8, 64);
        float rn = rsqrtf(sq * (1.0f / 64.0f) + EPS_);
        if (which == 0) rn *= 0.125f;  // fold attention scale into Q
#pragma unroll
        for (int ni = 0; ni < 4; ++ni)
          dst[(size_t)gr * C_ + c0 + ni * 16 + r] = f2bf(o[ni] * rn);
      }
  } else {
#pragma unroll
    for (int mi = 0; mi < 4; ++mi)
#pragma unroll
      for (int ni = 0; ni < 4; ++ni) {
        const int gc = c0 + ni * 16 + r;
#pragma unroll
        for (int j = 0; j < 4; ++j) {
          const int gr = m0 + wr * 64 + mi * 16 + quad * 4 + j;
          dst[(size_t)gr * C_ + gc] = f2bf(acc[mi][ni][j]);
        }
      }
  }
}

// ---------------- output GEMM: out = Y @ Wo^T (fp32 out) ----------------
__global__ __launch_bounds__(256) void gemm_out(const u16* __restrict__ X,
                                                const u16* __restrict__ W,
                                                float* __restrict__ Y,
                                                int M, int N, int K) {
  __shared__ short As[128 * 64];
  __shared__ short Bs[128 * 64];
  const int tid = threadIdx.x;
  const int lane = tid & 63;
  const int w = tid >> 6;
  const int wr = w >> 1, wc = w & 1;
  const int m0 = blockIdx.y * 128, n0 = blockIdx.x * 128;
  const int srow = lane >> 3;
  const int scol = (lane & 7) * 8;

  f32x4 acc[4][4];
#pragma unroll
  for (int mi = 0; mi < 4; ++mi)
#pragma unroll
    for (int ni = 0; ni < 4; ++ni)
      acc[mi][ni] = (f32x4){0.f, 0.f, 0.f, 0.f};

  const int r = lane & 15;
  const int quad = lane >> 4;

  bf16x8 av[4], bv[4];
#pragma unroll
  for (int i = 0; i < 4; ++i) {
    const int row = w * 32 + i * 8 + srow;
    av[i] = *(const bf16x8*)&X[(size_t)(m0 + row) * K + scol];
    bv[i] = *(const bf16x8*)&W[(size_t)(n0 + row) * K + scol];
  }

  for (int kt = 0; kt < K; kt += 64) {
#pragma unroll
    for (int i = 0; i < 4; ++i) {
      const int row = w * 32 + i * 8 + srow;
      *(bf16x8*)&As[row * 64 + scol] = av[i];
      *(bf16x8*)&Bs[row * 64 + scol] = bv[i];
    }
    __syncthreads();
    if (kt + 64 < K) {
#pragma unroll
      for (int i = 0; i < 4; ++i) {
        const int row = w * 32 + i * 8 + srow;
        av[i] = *(const bf16x8*)&X[(size_t)(m0 + row) * K + kt + 64 + scol];
        bv[i] = *(const bf16x8*)&W[(size_t)(n0 + row) * K + kt + 64 + scol];
      }
    }
#pragma unroll
    for (int kc = 0; kc < 2; ++kc) {
      const int ko = kc * 32 + quad * 8;
      bf16x8 a[4], b[4];
#pragma unroll
      for (int mi = 0; mi < 4; ++mi)
        a[mi] = *(const bf16x8*)&As[(wr * 64 + mi * 16 + r) * 64 + ko];
#pragma unroll
      for (int ni = 0; ni < 4; ++ni)
        b[ni] = *(const bf16x8*)&Bs[(wc * 64 + ni * 16 + r) * 64 + ko];
#pragma unroll
      for (int mi = 0; mi < 4; ++mi)
#pragma unroll
        for (int ni = 0; ni < 4; ++ni)
          acc[mi][ni] = __builtin_amdgcn_mfma_f32_16x16x32_bf16(a[mi], b[ni], acc[mi][ni], 0, 0, 0);
    }
    __syncthreads();
  }

#pragma unroll
  for (int mi = 0; mi < 4; ++mi)
#pragma unroll
    for (int ni = 0; ni < 4; ++ni) {
      const int gc = n0 + wc * 64 + ni * 16 + r;
#pragma unroll
      for (int j = 0; j < 4; ++j) {
        const int gr = m0 + wr * 64 + mi * 16 + quad * 4 + j;
        Y[(size_t)gr * N + gc] = acc[mi][ni][j];
      }
    }
}

// ---------------- MFMA flash attention, fixed-shift softmax ----------------
// |s| = |q̂·k| <= ||q̂||*||k|| = 1*8 = 8 (rmsnorm + folded scale) -> exp(s) safe,
// no running max needed; l reduced once in epilogue.
// Key<->slot permutation: slot = (key&15)*4 + (key>>4), applied to P-writes and
// Vt staging consistently -> P row writes become one ds_write_b64.
// grid=(T/128, B*H), block=256; wave w owns queries [w*32, w*32+32).
__global__ __launch_bounds__(256) void flash_mfma(const u16* __restrict__ Qb,
                                                  const u16* __restrict__ Kb,
                                                  const u16* __restrict__ Vb,
                                                  u16* __restrict__ Yb) {
  __shared__ u16 Ks[64][72];
  __shared__ u16 Vt[64][72];   // Vt[d][slot]
  __shared__ u16 Ps[128][72];  // Q staging, then P tiles (wave-local rows), [q][slot]
  const int tid = threadIdx.x;
  const int lane = tid & 63;
  const int w = tid >> 6;
  const int r = lane & 15;
  const int quad = lane >> 4;
  const int qt = blockIdx.x, bh = blockIdx.y;
  const int b = bh >> 4, h = bh & 15;
  const int srow = lane;
  const int sd0 = w * 16;
  const int vslot = (srow & 15) * 4 + (srow >> 4);  // slot for key=srow

  // stage Q tile (128 x 64): 2 threads per row
  {
    const int row = tid >> 1, half = tid & 1;
    const size_t g = ((size_t)((b * T_ + qt * 128 + row) * H_ + h)) * D_ + half * 32;
    *(bf16x8*)&Ps[row][half * 32]      = *(const bf16x8*)&Qb[g];
    *(bf16x8*)&Ps[row][half * 32 + 8]  = *(const bf16x8*)&Qb[g + 8];
    *(bf16x8*)&Ps[row][half * 32 + 16] = *(const bf16x8*)&Qb[g + 16];
    *(bf16x8*)&Ps[row][half * 32 + 24] = *(const bf16x8*)&Qb[g + 24];
  }
  __syncthreads();
  bf16x8 qf[2][2];
#pragma unroll
  for (int qg = 0; qg < 2; ++qg)
#pragma unroll
    for (int kc = 0; kc < 2; ++kc)
      qf[qg][kc] = *(const bf16x8*)&Ps[w * 32 + qg * 16 + r][kc * 32 + quad * 8];

  f32x4 oacc[2][4];
#pragma unroll
  for (int qg = 0; qg < 2; ++qg)
#pragma unroll
    for (int ni = 0; ni < 4; ++ni) oacc[qg][ni] = (f32x4){0.f, 0.f, 0.f, 0.f};
  float l_i[2][4];
#pragma unroll
  for (int qg = 0; qg < 2; ++qg)
#pragma unroll
    for (int j = 0; j < 4; ++j) l_i[qg][j] = 0.f;

  bf16x8 k0, k1, v0, v1;
  {
    const size_t g = ((size_t)((b * T_ + srow) * H_ + h)) * D_ + sd0;
    k0 = *(const bf16x8*)&Kb[g];
    k1 = *(const bf16x8*)&Kb[g + 8];
    v0 = *(const bf16x8*)&Vb[g];
    v1 = *(const bf16x8*)&Vb[g + 8];
  }

  for (int kt = 0; kt < T_; kt += 64) {
    *(bf16x8*)&Ks[srow][sd0] = k0;
    *(bf16x8*)&Ks[srow][sd0 + 8] = k1;
#pragma unroll
    for (int i = 0; i < 8; ++i) Vt[sd0 + i][vslot] = (u16)v0[i];
#pragma unroll
    for (int i = 0; i < 8; ++i) Vt[sd0 + 8 + i][vslot] = (u16)v1[i];
    __syncthreads();
    if (kt + 64 < T_) {
      const size_t g = ((size_t)((b * T_ + kt + 64 + srow) * H_ + h)) * D_ + sd0;
      k0 = *(const bf16x8*)&Kb[g];
      k1 = *(const bf16x8*)&Kb[g + 8];
      v0 = *(const bf16x8*)&Vb[g];
      v1 = *(const bf16x8*)&Vb[g + 8];
    }

#pragma unroll
    for (int qg = 0; qg < 2; ++qg) {
      f32x4 s[4];
#pragma unroll
      for (int ni = 0; ni < 4; ++ni) {
        s[ni] = (f32x4){0.f, 0.f, 0.f, 0.f};
#pragma unroll
        for (int kc = 0; kc < 2; ++kc) {
          bf16x8 kf = *(const bf16x8*)&Ks[ni * 16 + r][kc * 32 + quad * 8];
          s[ni] = __builtin_amdgcn_mfma_f32_16x16x32_bf16(qf[qg][kc], kf, s[ni], 0, 0, 0);
        }
      }
      // fixed-shift softmax: p = exp(s), per-lane partial l, packed P write
#pragma unroll
      for (int j = 0; j < 4; ++j) {
        const float p0 = __expf(s[0][j]);
        const float p1 = __expf(s[1][j]);
        const float p2 = __expf(s[2][j]);
        const float p3 = __expf(s[3][j]);
        l_i[qg][j] += (p0 + p1) + (p2 + p3);
        const int prow = w * 32 + qg * 16 + quad * 4 + j;
        u32 lo = (u32)f2bf(p0) | ((u32)f2bf(p1) << 16);
        u32 hi = (u32)f2bf(p2) | ((u32)f2bf(p3) << 16);
        uint2 pk = make_uint2(lo, hi);
        *(uint2*)&Ps[prow][r * 4] = pk;  // slots r*4 + ni
      }
      // O += P @ V (both operands in slot space)
#pragma unroll
      for (int kc = 0; kc < 2; ++kc) {
        bf16x8 pf = *(const bf16x8*)&Ps[w * 32 + qg * 16 + r][kc * 32 + quad * 8];
#pragma unroll
        for (int ni = 0; ni < 4; ++ni) {
          bf16x8 vf = *(const bf16x8*)&Vt[ni * 16 + r][kc * 32 + quad * 8];
          oacc[qg][ni] = __builtin_amdgcn_mfma_f32_16x16x32_bf16(pf, vf, oacc[qg][ni], 0, 0, 0);
        }
      }
    }
    __syncthreads();
  }

  // epilogue: reduce l across the 16 lanes holding each row, scale, store bf16
#pragma unroll
  for (int qg = 0; qg < 2; ++qg)
#pragma unroll
    for (int j = 0; j < 4; ++j) {
      float l = l_i[qg][j];
      l += __shfl_xor(l, 1, 64);
      l += __shfl_xor(l, 2, 64);
      l += __shfl_xor(l, 4, 64);
      l += __shfl_xor(l, 8, 64);
      const float inv = 1.0f / l;
      const int t = qt * 128 + w * 32 + qg * 16 + quad * 4 + j;
      const size_t gbase = ((size_t)((b * T_ + t) * H_ + h)) * D_;
#pragma unroll
      for (int ni = 0; ni < 4; ++ni)
        Yb[gbase + ni * 16 + r] = f2bf(oacc[qg][ni][j] * inv);
    }
}

extern "C" void kernel_launch(void* const* d_in, const int* in_sizes, int n_in,
                              void* d_out, int out_size, void* d_ws, size_t ws_size,
                              hipStream_t stream) {
  const float* x    = (const float*)d_in[0];
  const float* cosb = (const float*)d_in[1];
  const float* sinb = (const float*)d_in[2];
  const float* Wq   = (const float*)d_in[3];
  const float* Wk   = (const float*)d_in[4];
  const float* Wv   = (const float*)d_in[5];
  const float* Wo   = (const float*)d_in[6];
  float* out = (float*)d_out;

  const size_t NE = (size_t)B_ * T_ * C_;  // 8M elements
  const int CC = C_ * C_;                  // 1M elements
  // workspace (~72 MB): xb,qb,kb,vb bf16 (64 MB) + wqkv (6 MB) + wob (2 MB)
  u16* xb   = (u16*)d_ws;
  u16* qb   = xb + NE;
  u16* kb   = qb + NE;
  u16* vb   = kb + NE;
  u16* wqkv = vb + NE;
  u16* wob  = wqkv + 3 * (size_t)CC;
  u16* yb   = xb;  // xb dead after QKV GEMM; reuse for attention output

  const int M = B_ * T_;  // 8192

  cvt_bf16<<<(int)(NE / 1024), 256, 0, stream>>>(x, xb, (int)NE);
  dim3 wg(CC / 1024, 4);
  cvt_weights<<<wg, 256, 0, stream>>>(Wq, Wk, Wv, Wo, wqkv, wob, CC);

  dim3 qg(24, M / 128), gb(256);
  gemm_qkv<<<qg, gb, 0, stream>>>(xb, wqkv, qb, kb, vb, cosb, sinb, M, C_);

  dim3 fg(T_ / 128, B_ * H_);
  flash_mfma<<<fg, 256, 0, stream>>>(qb, kb, vb, yb);

  dim3 og(C_ / 128, M / 128);
  gemm_out<<<og, gb, 0, stream>>>(yb, wob, out, M, C_, C_);
}